// Round 1
// baseline (1449.364 us; speedup 1.0000x reference)
//
#include <hip/hip_runtime.h>
#include <hip/hip_bf16.h>

// Problem dims (hardcoded per reference)
#define BL_   131072   // B*H*W tokens
#define BW_   2048     // B * nW windows
#define NH_   8

typedef __attribute__((ext_vector_type(8))) short bf16x8;
typedef __attribute__((ext_vector_type(4))) float f32x4;

// ---------------- LN1 + roll(-4,-4) + window partition -> hwin bf16 [BW*64][256]
__global__ __launch_bounds__(256) void k_ln1_window(
    const float* __restrict__ x, const float* __restrict__ g1,
    const float* __restrict__ b1, __hip_bfloat16* __restrict__ hwin)
{
  const int wid = threadIdx.x >> 6, lane = threadIdx.x & 63;
  const int t = blockIdx.x * 4 + wid;          // window-ordered token id
  const int win = t >> 6, n = t & 63;
  const int b = win >> 10, wimg = win & 1023, wi = wimg >> 5, wj = wimg & 31;
  const int r = n >> 3, cc = n & 7;
  const int y = (wi * 8 + r + 4) & 255, xc = (wj * 8 + cc + 4) & 255;  // roll -4
  const float* src = x + ((size_t)(b * 65536 + y * 256 + xc)) * 256;
  float4 v = ((const float4*)src)[lane];
  float s  = v.x + v.y + v.z + v.w;
  float sq = v.x*v.x + v.y*v.y + v.z*v.z + v.w*v.w;
  for (int o = 32; o > 0; o >>= 1) { s += __shfl_xor(s, o); sq += __shfl_xor(sq, o); }
  const float mean = s * (1.f/256.f);
  const float var  = sq * (1.f/256.f) - mean*mean;
  const float rstd = rsqrtf(var + 1e-5f);
  const int c0 = lane * 4;
  float vv[4] = {v.x, v.y, v.z, v.w};
  union { __hip_bfloat16 h[4]; uint2 u; } ob;
  #pragma unroll
  for (int i = 0; i < 4; i++)
    ob.h[i] = __float2bfloat16((vv[i]-mean)*rstd*g1[c0+i] + b1[c0+i]);
  *(uint2*)(hwin + (size_t)t*256 + c0) = ob.u;
}

// ---------------- rel-pos bias gather: biasPre[nh][n][m]
__global__ __launch_bounds__(256) void k_bias_pre(
    const float* __restrict__ table, float* __restrict__ biasPre)
{
  const int idx = blockIdx.x * 256 + threadIdx.x;  // 8*64*64 = 32768
  const int nh = idx >> 12, n = (idx >> 6) & 63, m = idx & 63;
  const int dr = (n >> 3) - (m >> 3) + 7, dc = (n & 7) - (m & 7) + 7;
  biasPre[idx] = table[(dr*15 + dc)*8 + nh];
}

// ---------------- bf16 MFMA GEMM, 64x64 tile, BK=32, 4 waves (each 16x64 strip)
// MODE 0: +bias, store bf16 in head layout [win][nh][n][d]   (QKV)
// MODE 1: +bias, exact GELU, store bf16 row-major [M][Nw]    (FC1)
// MODE 2: +bias, +z residual (bf16), store fp32 [M][256]     (FC2 -> d_out)
template<int MODE>
__global__ __launch_bounds__(256) void k_gemm(
    const __hip_bfloat16* __restrict__ A, const float* __restrict__ Wt,
    const float* __restrict__ bias, void* __restrict__ outp,
    const __hip_bfloat16* __restrict__ zres, int M, int K, int Nw)
{
  __shared__ __align__(16) __hip_bfloat16 Alds[64*40];  // [row][k] pad 32->40
  __shared__ __align__(16) __hip_bfloat16 Blds[64*40];  // [col][k] (B transposed)
  const int tid = threadIdx.x;
  const int mtile = blockIdx.y * 64, ntile = blockIdx.x * 64;
  const int wave = tid >> 6, lane = tid & 63, quad = lane >> 4, ln = lane & 15;
  const int srow = tid >> 2, skc = (tid & 3) << 3;

  f32x4 acc[4];
  #pragma unroll
  for (int tt = 0; tt < 4; tt++)
    #pragma unroll
    for (int i = 0; i < 4; i++) acc[tt][i] = 0.f;

  for (int k0 = 0; k0 < K; k0 += 32) {
    // stage A: 64 rows x 32 k (bf16 16B chunks)
    uint4 av = *(const uint4*)(A + (size_t)(mtile + srow) * K + k0 + skc);
    *(uint4*)&Alds[srow*40 + skc] = av;
    // stage B transposed: col 'srow', 8 k's; convert fp32->bf16
    union { __hip_bfloat16 h[8]; uint4 u; } hb;
    #pragma unroll
    for (int j = 0; j < 8; j++)
      hb.h[j] = __float2bfloat16(Wt[(size_t)(k0 + skc + j) * Nw + ntile + srow]);
    *(uint4*)&Blds[srow*40 + skc] = hb.u;
    __syncthreads();
    // a_frag: A[m=ln + wave*16][k=quad*8+j]; b_frag: B[k=quad*8+j][n=ln + tt*16]
    bf16x8 a = *(const bf16x8*)&Alds[(wave*16 + ln)*40 + quad*8];
    #pragma unroll
    for (int tt = 0; tt < 4; tt++) {
      bf16x8 b = *(const bf16x8*)&Blds[(tt*16 + ln)*40 + quad*8];
      acc[tt] = __builtin_amdgcn_mfma_f32_16x16x32_bf16(a, b, acc[tt], 0, 0, 0);
    }
    __syncthreads();
  }

  // D[m = quad*4+reg][n = ln]
  #pragma unroll
  for (int tt = 0; tt < 4; tt++) {
    const int cB = ntile + tt*16 + ln;
    const float bs = bias[cB];
    #pragma unroll
    for (int r = 0; r < 4; r++) {
      const int mB = mtile + wave*16 + quad*4 + r;
      float val = acc[tt][r] + bs;
      if (MODE == 0) {
        const int win = mB >> 6, ntok = mB & 63, nh = cB >> 5, d = cB & 31;
        ((__hip_bfloat16*)outp)[(((size_t)win*8 + nh)*64 + ntok)*32 + d] = __float2bfloat16(val);
      } else if (MODE == 1) {
        val = 0.5f * val * (1.f + erff(val * 0.70710678118654752f));
        ((__hip_bfloat16*)outp)[(size_t)mB * Nw + cB] = __float2bfloat16(val);
      } else {
        val += __bfloat162float(zres[(size_t)mB * 256 + cB]);
        ((float*)outp)[(size_t)mB * 256 + cB] = val;
      }
    }
  }
}

// ---------------- windowed attention, one block(64 thr) per (window, head)
__global__ __launch_bounds__(64) void k_attn(
    const __hip_bfloat16* __restrict__ q, const __hip_bfloat16* __restrict__ k,
    const __hip_bfloat16* __restrict__ v, const float* __restrict__ biasPre,
    __hip_bfloat16* __restrict__ attnV)
{
  const int blk = blockIdx.x;
  const int win = blk >> 3, nh = blk & 7;
  const int n = threadIdx.x;                    // query token
  __shared__ float kld[64*32];
  __shared__ float vld[64*32];
  __shared__ int   regS[64];
  const size_t base = ((size_t)win * 8 + nh) * 2048;
  const __hip_bfloat16* kr = k + base + n*32;
  const __hip_bfloat16* vr = v + base + n*32;
  #pragma unroll
  for (int d = 0; d < 32; d++) {
    kld[n*32 + d] = __bfloat162float(kr[d]);
    vld[n*32 + d] = __bfloat162float(vr[d]);
  }
  // shift-mask region of this token (mask built on rolled image coords)
  const int wimg = win & 1023, wi = wimg >> 5, wj = wimg & 31;
  const int yy = wi*8 + (n>>3), xx = wj*8 + (n&7);
  const int ry = (yy < 248) ? 0 : ((yy < 252) ? 1 : 2);
  const int rx = (xx < 248) ? 0 : ((xx < 252) ? 1 : 2);
  regS[n] = ry*3 + rx;
  float qr[32];
  const __hip_bfloat16* qp = q + base + n*32;
  #pragma unroll
  for (int d = 0; d < 32; d++) qr[d] = __bfloat162float(qp[d]);
  __syncthreads();

  float sc[64];
  const float scale = 0.17677669529663687f;  // 1/sqrt(32)
  const int myreg = regS[n];
  const float* bptr = biasPre + ((size_t)nh << 12) + (n << 6);
  float mx = -1e30f;
  for (int m = 0; m < 64; m++) {
    float sacc = 0.f;
    #pragma unroll
    for (int d = 0; d < 32; d++) sacc += qr[d] * kld[m*32 + d];
    sacc = sacc * scale + bptr[m];
    if (regS[m] != myreg) sacc -= 100.f;
    sc[m] = sacc;
    mx = fmaxf(mx, sacc);
  }
  float ssum = 0.f;
  for (int m = 0; m < 64; m++) { sc[m] = __expf(sc[m] - mx); ssum += sc[m]; }
  const float inv = 1.f / ssum;
  float o[32];
  #pragma unroll
  for (int d = 0; d < 32; d++) o[d] = 0.f;
  for (int m = 0; m < 64; m++) {
    const float p = sc[m] * inv;
    #pragma unroll
    for (int d = 0; d < 32; d++) o[d] += p * vld[m*32 + d];
  }
  __hip_bfloat16* op = attnV + base + n*32;
  #pragma unroll
  for (int d = 0; d < 32; d++) op[d] = __float2bfloat16(o[d]);
}

// ---------------- gather(scrambled windows, roll +4) + residual x + LN2 -> z bf16
__global__ __launch_bounds__(256) void k_add_ln2(
    const float* __restrict__ x, const __hip_bfloat16* __restrict__ attnV,
    const float* __restrict__ g2, const float* __restrict__ b2,
    __hip_bfloat16* __restrict__ z)
{
  const int wid = threadIdx.x >> 6, lane = threadIdx.x & 63;
  const int t = blockIdx.x * 4 + wid;          // output token (b, y, x)
  const int b = t >> 16, l = t & 65535, y = l >> 8, xc = l & 255;
  const int y2 = (y + 252) & 255, x2 = (xc + 252) & 255;  // inverse roll +4
  const int wi = y2 >> 3, nh = y2 & 7, wj = x2 >> 3, j = x2 & 7;
  const int c0 = lane * 4;
  // faithful-to-source reshape: c -> token n = j*8 + c/32, d = c%32, head = y2%8
  const int n = j*8 + (c0 >> 5), d = c0 & 31;
  const size_t aidx = ((((size_t)(b*1024 + wi*32 + wj))*8 + nh)*64 + n)*32 + d;
  float4 xv = ((const float4*)(x + (size_t)t*256))[lane];
  float sv[4];
  sv[0] = xv.x + __bfloat162float(attnV[aidx+0]);
  sv[1] = xv.y + __bfloat162float(attnV[aidx+1]);
  sv[2] = xv.z + __bfloat162float(attnV[aidx+2]);
  sv[3] = xv.w + __bfloat162float(attnV[aidx+3]);
  float s  = sv[0]+sv[1]+sv[2]+sv[3];
  float sq = sv[0]*sv[0]+sv[1]*sv[1]+sv[2]*sv[2]+sv[3]*sv[3];
  for (int o = 32; o > 0; o >>= 1) { s += __shfl_xor(s, o); sq += __shfl_xor(sq, o); }
  const float mean = s*(1.f/256.f);
  const float var  = sq*(1.f/256.f) - mean*mean;
  const float rstd = rsqrtf(var + 1e-5f);
  union { __hip_bfloat16 h[4]; uint2 u; } ob;
  #pragma unroll
  for (int i = 0; i < 4; i++)
    ob.h[i] = __float2bfloat16((sv[i]-mean)*rstd*g2[c0+i] + b2[c0+i]);
  *(uint2*)(z + (size_t)t*256 + c0) = ob.u;
}

extern "C" void kernel_launch(void* const* d_in, const int* in_sizes, int n_in,
                              void* d_out, int out_size, void* d_ws, size_t ws_size,
                              hipStream_t stream)
{
  (void)in_sizes; (void)n_in; (void)out_size; (void)ws_size;
  const float* x   = (const float*)d_in[0];
  const float* g1  = (const float*)d_in[1];
  const float* b1  = (const float*)d_in[2];
  const float* wq  = (const float*)d_in[3];
  const float* bq  = (const float*)d_in[4];
  const float* wk  = (const float*)d_in[5];
  const float* bk  = (const float*)d_in[6];
  const float* wv  = (const float*)d_in[7];
  const float* bv  = (const float*)d_in[8];
  const float* tbl = (const float*)d_in[9];
  const float* g2  = (const float*)d_in[10];
  const float* b2  = (const float*)d_in[11];
  const float* wf1 = (const float*)d_in[12];
  const float* bf1 = (const float*)d_in[13];
  const float* wf2 = (const float*)d_in[14];
  const float* bf2 = (const float*)d_in[15];

  char* ws = (char*)d_ws;
  const size_t MB = 1024ull*1024ull;
  // lifetimes: hwin,q,k,v dead before fc1 writes tbuf over [0,256MB)
  __hip_bfloat16* hwin  = (__hip_bfloat16*)(ws);             // 64MB
  __hip_bfloat16* qb    = (__hip_bfloat16*)(ws + 64*MB);     // 64MB
  __hip_bfloat16* kb    = (__hip_bfloat16*)(ws + 128*MB);    // 64MB
  __hip_bfloat16* vb    = (__hip_bfloat16*)(ws + 192*MB);    // 64MB
  __hip_bfloat16* tbuf  = (__hip_bfloat16*)(ws);             // 256MB (fc1 out)
  __hip_bfloat16* attnV = (__hip_bfloat16*)(ws + 256*MB);    // 64MB
  __hip_bfloat16* zb    = (__hip_bfloat16*)(ws + 320*MB);    // 64MB
  float*          biasP = (float*)(ws + 384*MB);             // 128KB

  k_ln1_window<<<BL_/4, 256, 0, stream>>>(x, g1, b1, hwin);
  k_bias_pre<<<128, 256, 0, stream>>>(tbl, biasP);
  dim3 g256(4, 2048);
  k_gemm<0><<<g256, 256, 0, stream>>>(hwin, wq, bq, qb, nullptr, BL_, 256, 256);
  k_gemm<0><<<g256, 256, 0, stream>>>(hwin, wk, bk, kb, nullptr, BL_, 256, 256);
  k_gemm<0><<<g256, 256, 0, stream>>>(hwin, wv, bv, vb, nullptr, BL_, 256, 256);
  k_attn<<<BW_*NH_, 64, 0, stream>>>(qb, kb, vb, biasP, attnV);
  k_add_ln2<<<BL_/4, 256, 0, stream>>>(x, attnV, g2, b2, zb);
  dim3 g1024(16, 2048);
  k_gemm<1><<<g1024, 256, 0, stream>>>(zb, wf1, bf1, tbuf, nullptr, BL_, 256, 1024);
  k_gemm<2><<<g256, 256, 0, stream>>>(tbuf, wf2, bf2, d_out, zb, BL_, 1024, 256);
}

// Round 2
// 898.100 us; speedup vs baseline: 1.6138x; 1.6138x over previous
//
#include <hip/hip_runtime.h>
#include <hip/hip_bf16.h>

#define BL_   131072   // B*H*W tokens
#define BW_   2048     // B * nW windows

typedef __attribute__((ext_vector_type(8))) short bf16x8;
typedef __attribute__((ext_vector_type(4))) float f32x4;

typedef __attribute__((address_space(1))) void gvoid;
typedef __attribute__((address_space(3))) void lvoid;

__device__ __forceinline__ void gload_lds16(const void* g, void* l) {
  __builtin_amdgcn_global_load_lds((gvoid*)g, (lvoid*)l, 16, 0, 0);
}

// ---------------- weight pack: fp32 [K][N] -> bf16 [N][K] (B-transposed), qkv fused
__global__ __launch_bounds__(256) void k_pack(
    const float* __restrict__ wq, const float* __restrict__ wk,
    const float* __restrict__ wv, const float* __restrict__ wf1,
    const float* __restrict__ wf2, __hip_bfloat16* __restrict__ wqkvT,
    __hip_bfloat16* __restrict__ wf1T, __hip_bfloat16* __restrict__ wf2T)
{
  const int id = blockIdx.x * 256 + threadIdx.x;   // 720896 total
  if (id < 196608) {                     // wqkvT [768][256]
    const int n = id >> 8, kk = id & 255;
    const int sec = n >> 8, c = n & 255;
    const float* W = sec == 0 ? wq : (sec == 1 ? wk : wv);
    wqkvT[id] = __float2bfloat16(W[kk * 256 + c]);
  } else if (id < 458752) {              // wf1T [1024][256]
    const int t = id - 196608;
    const int n = t >> 8, kk = t & 255;
    wf1T[t] = __float2bfloat16(wf1[kk * 1024 + n]);
  } else {                               // wf2T [256][1024]
    const int t = id - 458752;
    const int n = t >> 10, kk = t & 1023;
    wf2T[t] = __float2bfloat16(wf2[kk * 256 + n]);
  }
}

// ---------------- rel-pos bias gather: biasPre[nh][n][m]
__global__ __launch_bounds__(256) void k_bias_pre(
    const float* __restrict__ table, float* __restrict__ biasPre)
{
  const int idx = blockIdx.x * 256 + threadIdx.x;  // 32768
  const int nh = idx >> 12, n = (idx >> 6) & 63, m = idx & 63;
  const int dr = (n >> 3) - (m >> 3) + 7, dc = (n & 7) - (m & 7) + 7;
  biasPre[idx] = table[(dr * 15 + dc) * 8 + nh];
}

// ---------------- LN1 + roll(-4,-4) + window partition -> hwin bf16 [BW*64][256]
__global__ __launch_bounds__(256) void k_ln1_window(
    const float* __restrict__ x, const float* __restrict__ g1,
    const float* __restrict__ b1, __hip_bfloat16* __restrict__ hwin)
{
  const int wid = threadIdx.x >> 6, lane = threadIdx.x & 63;
  const int t = blockIdx.x * 4 + wid;
  const int win = t >> 6, n = t & 63;
  const int b = win >> 10, wimg = win & 1023, wi = wimg >> 5, wj = wimg & 31;
  const int r = n >> 3, cc = n & 7;
  const int y = (wi * 8 + r + 4) & 255, xc = (wj * 8 + cc + 4) & 255;
  const float* src = x + ((size_t)(b * 65536 + y * 256 + xc)) * 256;
  float4 v = ((const float4*)src)[lane];
  float s  = v.x + v.y + v.z + v.w;
  float sq = v.x*v.x + v.y*v.y + v.z*v.z + v.w*v.w;
  for (int o = 32; o > 0; o >>= 1) { s += __shfl_xor(s, o); sq += __shfl_xor(sq, o); }
  const float mean = s * (1.f/256.f);
  const float var  = sq * (1.f/256.f) - mean*mean;
  const float rstd = rsqrtf(var + 1e-5f);
  const int c0 = lane * 4;
  float vv[4] = {v.x, v.y, v.z, v.w};
  union { __hip_bfloat16 h[4]; uint2 u; } ob;
  #pragma unroll
  for (int i = 0; i < 4; i++)
    ob.h[i] = __float2bfloat16((vv[i]-mean)*rstd*g1[c0+i] + b1[c0+i]);
  *(uint2*)(hwin + (size_t)t*256 + c0) = ob.u;
}

// ---------------- 128x128 bf16 MFMA GEMM, BK=32, global_load_lds, XOR-swizzled LDS
// MODE 0: QKV fused (N=768): +bias(q|k|v), q/k head layout, v TRANSPOSED [win][nh][d][tok]
// MODE 1: FC1: +bias, exact GELU, bf16 [M][1024]
// MODE 2: FC2: +bias, +zres, fp32 [M][256] (d_out)
template<int MODE>
__global__ __launch_bounds__(256) void k_gemm128(
    const __hip_bfloat16* __restrict__ A, const __hip_bfloat16* __restrict__ Bt,
    const float* __restrict__ bias0, const float* __restrict__ bias1,
    const float* __restrict__ bias2, void* __restrict__ o0, void* __restrict__ o1,
    void* __restrict__ o2, const __hip_bfloat16* __restrict__ zres, const int K)
{
  __shared__ __align__(16) __hip_bfloat16 Alds[128*32];
  __shared__ __align__(16) __hip_bfloat16 Blds[128*32];
  const int tid = threadIdx.x;
  const int wid = tid >> 6, lane = tid & 63, quad = lane >> 4, ln = lane & 15;
  const int mtile = blockIdx.y * 128, ntile = blockIdx.x * 128;
  const int wrow = (wid >> 1) * 64, wcol = (wid & 1) * 64;

  f32x4 acc[4][4];
  #pragma unroll
  for (int mt = 0; mt < 4; mt++)
    #pragma unroll
    for (int nt = 0; nt < 4; nt++)
      acc[mt][nt] = (f32x4){0.f, 0.f, 0.f, 0.f};

  // staging geometry: chunk = wid*128 + c*64 + lane; LDS gets base+lane*16 (HW)
  int srow[2], skc[2], sbase[2];
  #pragma unroll
  for (int c = 0; c < 2; c++) {
    const int chunk = wid*128 + c*64 + lane;
    srow[c] = chunk >> 2;
    skc[c]  = (chunk & 3) ^ ((srow[c] >> 1) & 3);   // XOR swizzle slot->kc
    sbase[c] = (wid*128 + c*64) * 8;                // wave-uniform LDS elt offset
  }

  for (int k0 = 0; k0 < K; k0 += 32) {
    #pragma unroll
    for (int c = 0; c < 2; c++) {
      gload_lds16(A + (size_t)(mtile + srow[c]) * K + k0 + skc[c]*8, Alds + sbase[c]);
      gload_lds16(Bt + (size_t)(ntile + srow[c]) * K + k0 + skc[c]*8, Blds + sbase[c]);
    }
    __syncthreads();
    bf16x8 af[4], bfr[4];
    #pragma unroll
    for (int mt = 0; mt < 4; mt++) {
      const int r = wrow + mt*16 + ln;
      af[mt] = *(const bf16x8*)&Alds[r*32 + (quad ^ ((r >> 1) & 3))*8];
    }
    #pragma unroll
    for (int nt = 0; nt < 4; nt++) {
      const int r = wcol + nt*16 + ln;
      bfr[nt] = *(const bf16x8*)&Blds[r*32 + (quad ^ ((r >> 1) & 3))*8];
    }
    #pragma unroll
    for (int mt = 0; mt < 4; mt++)
      #pragma unroll
      for (int nt = 0; nt < 4; nt++)
        acc[mt][nt] = __builtin_amdgcn_mfma_f32_16x16x32_bf16(af[mt], bfr[nt], acc[mt][nt], 0, 0, 0);
    __syncthreads();
  }

  #pragma unroll
  for (int mt = 0; mt < 4; mt++) {
    #pragma unroll
    for (int nt = 0; nt < 4; nt++) {
      const int cB = ntile + wcol + nt*16 + ln;
      #pragma unroll
      for (int r = 0; r < 4; r++) {
        const int mB = mtile + wrow + mt*16 + quad*4 + r;
        float val = acc[mt][nt][r];
        if (MODE == 0) {
          const int sec = cB >> 8, c = cB & 255, nh = c >> 5, d = c & 31;
          val += (sec == 0 ? bias0 : (sec == 1 ? bias1 : bias2))[c];
          const int win = mB >> 6, tok = mB & 63;
          const __hip_bfloat16 hv = __float2bfloat16(val);
          if (sec < 2) {
            __hip_bfloat16* dst = (__hip_bfloat16*)(sec == 0 ? o0 : o1);
            dst[(((size_t)win*8 + nh)*64 + tok)*32 + d] = hv;
          } else {
            ((__hip_bfloat16*)o2)[(((size_t)win*8 + nh)*32 + d)*64 + tok] = hv;
          }
        } else if (MODE == 1) {
          val += bias0[cB];
          val = 0.5f * val * (1.f + erff(val * 0.70710678118654752f));
          ((__hip_bfloat16*)o0)[(size_t)mB * 1024 + cB] = __float2bfloat16(val);
        } else {
          val += bias0[cB] + __bfloat162float(zres[(size_t)mB * 256 + cB]);
          ((float*)o0)[(size_t)mB * 256 + cB] = val;
        }
      }
    }
  }
}

// ---------------- MFMA windowed attention: block=256 (4 waves) per window, 2 heads/wave
__global__ __launch_bounds__(256) void k_attn(
    const __hip_bfloat16* __restrict__ q, const __hip_bfloat16* __restrict__ kbuf,
    const __hip_bfloat16* __restrict__ vt, const float* __restrict__ biasPre,
    __hip_bfloat16* __restrict__ attnV)
{
  __shared__ __align__(16) __hip_bfloat16 Plds[4][64*72];  // per-wave, +8 pad kills b128 conflicts
  const int tid = threadIdx.x, wv = tid >> 6, lane = tid & 63;
  const int quad = lane >> 4, ln = lane & 15;
  const int win = blockIdx.x;
  const int wimg = win & 1023, wi = wimg >> 5, wj = wimg & 31;

  // shift-mask regions (rolled-image coords), hoisted per block
  int colreg[4], rowreg[4][4];
  #pragma unroll
  for (int nt = 0; nt < 4; nt++) {
    const int t = nt*16 + ln;
    const int y = wi*8 + (t >> 3), x = wj*8 + (t & 7);
    colreg[nt] = ((y < 248) ? 0 : ((y < 252) ? 1 : 2)) * 3 +
                 ((x < 248) ? 0 : ((x < 252) ? 1 : 2));
  }
  #pragma unroll
  for (int mt = 0; mt < 4; mt++)
    #pragma unroll
    for (int r = 0; r < 4; r++) {
      const int t = mt*16 + quad*4 + r;
      const int y = wi*8 + (t >> 3), x = wj*8 + (t & 7);
      rowreg[mt][r] = ((y < 248) ? 0 : ((y < 252) ? 1 : 2)) * 3 +
                      ((x < 248) ? 0 : ((x < 252) ? 1 : 2));
    }

  for (int hh = 0; hh < 2; hh++) {
    const int h = wv*2 + hh;
    const size_t base = ((size_t)win*8 + h)*2048;

    // S = Q K^T : direct global fragment loads
    bf16x8 af[4], bfr[4];
    #pragma unroll
    for (int mt = 0; mt < 4; mt++)
      af[mt] = *(const bf16x8*)(q + base + (size_t)(mt*16 + ln)*32 + quad*8);
    #pragma unroll
    for (int nt = 0; nt < 4; nt++)
      bfr[nt] = *(const bf16x8*)(kbuf + base + (size_t)(nt*16 + ln)*32 + quad*8);
    f32x4 s[4][4];
    #pragma unroll
    for (int mt = 0; mt < 4; mt++)
      #pragma unroll
      for (int nt = 0; nt < 4; nt++) {
        s[mt][nt] = (f32x4){0.f, 0.f, 0.f, 0.f};
        s[mt][nt] = __builtin_amdgcn_mfma_f32_16x16x32_bf16(af[mt], bfr[nt], s[mt][nt], 0, 0, 0);
      }

    // scale + rel-pos bias + shift mask
    const float* bp = biasPre + (h << 12);
    #pragma unroll
    for (int mt = 0; mt < 4; mt++)
      #pragma unroll
      for (int nt = 0; nt < 4; nt++)
        #pragma unroll
        for (int r = 0; r < 4; r++) {
          const int row = mt*16 + quad*4 + r, col = nt*16 + ln;
          float val = s[mt][nt][r] * 0.17677669529663687f + bp[row*64 + col];
          if (rowreg[mt][r] != colreg[nt]) val -= 100.f;
          s[mt][nt][r] = val;
        }

    // softmax over cols (nt in-lane x ln across lanes)
    #pragma unroll
    for (int mt = 0; mt < 4; mt++) {
      f32x4 mx;
      #pragma unroll
      for (int r = 0; r < 4; r++)
        mx[r] = fmaxf(fmaxf(s[mt][0][r], s[mt][1][r]), fmaxf(s[mt][2][r], s[mt][3][r]));
      #pragma unroll
      for (int msk = 1; msk <= 8; msk <<= 1)
        #pragma unroll
        for (int r = 0; r < 4; r++) mx[r] = fmaxf(mx[r], __shfl_xor(mx[r], msk));
      f32x4 sum = (f32x4){0.f, 0.f, 0.f, 0.f};
      #pragma unroll
      for (int nt = 0; nt < 4; nt++)
        #pragma unroll
        for (int r = 0; r < 4; r++) {
          s[mt][nt][r] = __expf(s[mt][nt][r] - mx[r]);
          sum[r] += s[mt][nt][r];
        }
      #pragma unroll
      for (int msk = 1; msk <= 8; msk <<= 1)
        #pragma unroll
        for (int r = 0; r < 4; r++) sum[r] += __shfl_xor(sum[r], msk);
      f32x4 inv;
      #pragma unroll
      for (int r = 0; r < 4; r++) inv[r] = 1.f / sum[r];
      // P -> per-wave LDS in A-layout source form (row-major [m][64])
      #pragma unroll
      for (int nt = 0; nt < 4; nt++)
        #pragma unroll
        for (int r = 0; r < 4; r++)
          Plds[wv][(mt*16 + quad*4 + r)*72 + nt*16 + ln] =
              __float2bfloat16(s[mt][nt][r] * inv[r]);
    }
    __syncthreads();

    // O = P V : P a-frags from LDS, V b-frags direct (vt transposed [nh][d][tok])
    f32x4 o[4][2];
    #pragma unroll
    for (int mt = 0; mt < 4; mt++)
      #pragma unroll
      for (int dt = 0; dt < 2; dt++) o[mt][dt] = (f32x4){0.f, 0.f, 0.f, 0.f};
    #pragma unroll
    for (int ks = 0; ks < 2; ks++) {
      bf16x8 pa[4];
      #pragma unroll
      for (int mt = 0; mt < 4; mt++)
        pa[mt] = *(const bf16x8*)&Plds[wv][(mt*16 + ln)*72 + ks*32 + quad*8];
      #pragma unroll
      for (int dt = 0; dt < 2; dt++) {
        const bf16x8 vb = *(const bf16x8*)(vt + base + (size_t)(dt*16 + ln)*64 + ks*32 + quad*8);
        #pragma unroll
        for (int mt = 0; mt < 4; mt++)
          o[mt][dt] = __builtin_amdgcn_mfma_f32_16x16x32_bf16(pa[mt], vb, o[mt][dt], 0, 0, 0);
      }
    }
    #pragma unroll
    for (int mt = 0; mt < 4; mt++)
      #pragma unroll
      for (int dt = 0; dt < 2; dt++)
        #pragma unroll
        for (int r = 0; r < 4; r++)
          attnV[base + (size_t)(mt*16 + quad*4 + r)*32 + dt*16 + ln] =
              __float2bfloat16(o[mt][dt][r]);
    __syncthreads();
  }
}

// ---------------- gather(scrambled windows, roll +4) + residual + LN2 -> z bf16
__global__ __launch_bounds__(256) void k_add_ln2(
    const float* __restrict__ x, const __hip_bfloat16* __restrict__ attnV,
    const float* __restrict__ g2, const float* __restrict__ b2,
    __hip_bfloat16* __restrict__ z)
{
  const int wid = threadIdx.x >> 6, lane = threadIdx.x & 63;
  const int t = blockIdx.x * 4 + wid;
  const int b = t >> 16, l = t & 65535, y = l >> 8, xc = l & 255;
  const int y2 = (y + 252) & 255, x2 = (xc + 252) & 255;
  const int wi = y2 >> 3, nh = y2 & 7, wj = x2 >> 3, j = x2 & 7;
  const int c0 = lane * 4;
  const int n = j*8 + (c0 >> 5), d = c0 & 31;
  const size_t aidx = ((((size_t)(b*1024 + wi*32 + wj))*8 + nh)*64 + n)*32 + d;
  float4 xv = ((const float4*)(x + (size_t)t*256))[lane];
  float sv[4];
  sv[0] = xv.x + __bfloat162float(attnV[aidx+0]);
  sv[1] = xv.y + __bfloat162float(attnV[aidx+1]);
  sv[2] = xv.z + __bfloat162float(attnV[aidx+2]);
  sv[3] = xv.w + __bfloat162float(attnV[aidx+3]);
  float s  = sv[0]+sv[1]+sv[2]+sv[3];
  float sq = sv[0]*sv[0]+sv[1]*sv[1]+sv[2]*sv[2]+sv[3]*sv[3];
  for (int o = 32; o > 0; o >>= 1) { s += __shfl_xor(s, o); sq += __shfl_xor(sq, o); }
  const float mean = s*(1.f/256.f);
  const float var  = sq*(1.f/256.f) - mean*mean;
  const float rstd = rsqrtf(var + 1e-5f);
  union { __hip_bfloat16 h[4]; uint2 u; } ob;
  #pragma unroll
  for (int i = 0; i < 4; i++)
    ob.h[i] = __float2bfloat16((sv[i]-mean)*rstd*g2[c0+i] + b2[c0+i]);
  *(uint2*)(z + (size_t)t*256 + c0) = ob.u;
}

extern "C" void kernel_launch(void* const* d_in, const int* in_sizes, int n_in,
                              void* d_out, int out_size, void* d_ws, size_t ws_size,
                              hipStream_t stream)
{
  (void)in_sizes; (void)n_in; (void)out_size; (void)ws_size;
  const float* x   = (const float*)d_in[0];
  const float* g1  = (const float*)d_in[1];
  const float* b1  = (const float*)d_in[2];
  const float* wq  = (const float*)d_in[3];
  const float* bq  = (const float*)d_in[4];
  const float* wk  = (const float*)d_in[5];
  const float* bk  = (const float*)d_in[6];
  const float* wv  = (const float*)d_in[7];
  const float* bv  = (const float*)d_in[8];
  const float* tbl = (const float*)d_in[9];
  const float* g2  = (const float*)d_in[10];
  const float* b2  = (const float*)d_in[11];
  const float* wf1 = (const float*)d_in[12];
  const float* bf1 = (const float*)d_in[13];
  const float* wf2 = (const float*)d_in[14];
  const float* bf2 = (const float*)d_in[15];

  char* ws = (char*)d_ws;
  const size_t MB = 1024ull*1024ull;
  __hip_bfloat16* hwin  = (__hip_bfloat16*)(ws);             // 64MB
  __hip_bfloat16* qb    = (__hip_bfloat16*)(ws + 64*MB);     // 64MB
  __hip_bfloat16* kb    = (__hip_bfloat16*)(ws + 128*MB);    // 64MB
  __hip_bfloat16* vtb   = (__hip_bfloat16*)(ws + 192*MB);    // 64MB (V transposed)
  __hip_bfloat16* tbuf  = (__hip_bfloat16*)(ws);             // 256MB (aliases hwin/q/k/v after attn)
  __hip_bfloat16* attnV = (__hip_bfloat16*)(ws + 256*MB);    // 64MB
  __hip_bfloat16* zb    = (__hip_bfloat16*)(ws + 320*MB);    // 64MB
  float*          biasP = (float*)(ws + 384*MB);             // 128KB
  __hip_bfloat16* wf2T  = (__hip_bfloat16*)(ws + 384*MB + 128*1024);  // 512KB
  // small pack scratch inside d_out (dead before FC2 writes d_out)
  __hip_bfloat16* wqkvT = (__hip_bfloat16*)d_out;                      // 384KB
  __hip_bfloat16* wf1T  = (__hip_bfloat16*)((char*)d_out + 512*1024);  // 512KB

  k_pack<<<2816, 256, 0, stream>>>(wq, wk, wv, wf1, wf2, wqkvT, wf1T, wf2T);
  k_bias_pre<<<128, 256, 0, stream>>>(tbl, biasP);
  k_ln1_window<<<BL_/4, 256, 0, stream>>>(x, g1, b1, hwin);
  k_gemm128<0><<<dim3(6, 1024), 256, 0, stream>>>(hwin, wqkvT, bq, bk, bv,
                                                  qb, kb, vtb, nullptr, 256);
  k_attn<<<BW_, 256, 0, stream>>>(qb, kb, vtb, biasP, attnV);
  k_add_ln2<<<BL_/4, 256, 0, stream>>>(x, attnV, g2, b2, zb);
  k_gemm128<1><<<dim3(8, 1024), 256, 0, stream>>>(zb, wf1T, bf1, nullptr, nullptr,
                                                  tbuf, nullptr, nullptr, nullptr, 256);
  k_gemm128<2><<<dim3(2, 1024), 256, 0, stream>>>(tbuf, wf2T, bf2, nullptr, nullptr,
                                                  d_out, nullptr, nullptr, zb, 1024);
}

// Round 3
// 812.571 us; speedup vs baseline: 1.7837x; 1.1053x over previous
//
#include <hip/hip_runtime.h>
#include <hip/hip_bf16.h>

#define BW_   2048     // B * nW windows

typedef __attribute__((ext_vector_type(8))) short bf16x8;
typedef __attribute__((ext_vector_type(4))) float f32x4;

typedef __attribute__((address_space(1))) void gvoid;
typedef __attribute__((address_space(3))) void lvoid;

__device__ __forceinline__ void gload_lds16(const void* g, void* l) {
  __builtin_amdgcn_global_load_lds((gvoid*)g, (lvoid*)l, 16, 0, 0);
}

__device__ __forceinline__ float gelu_fast(float u) {
  // tanh-form GELU: u * sigmoid(1.5957691(u + 0.044715 u^3)); max err ~3e-4
  const float c = u + 0.044715f * u * u * u;
  return u / (1.f + __expf(-1.5957691216057308f * c));
}

// ---------------- weight pack: fp32 [K][N] -> bf16 [N][K] (B-transposed), qkv fused
__global__ __launch_bounds__(256) void k_pack(
    const float* __restrict__ wq, const float* __restrict__ wk,
    const float* __restrict__ wv, const float* __restrict__ wf1,
    const float* __restrict__ wf2, __hip_bfloat16* __restrict__ wqkvT,
    __hip_bfloat16* __restrict__ wf1T, __hip_bfloat16* __restrict__ wf2T)
{
  const int id = blockIdx.x * 256 + threadIdx.x;   // 720896 total
  if (id < 196608) {                     // wqkvT [768][256]
    const int n = id >> 8, kk = id & 255;
    const int sec = n >> 8, c = n & 255;
    const float* W = sec == 0 ? wq : (sec == 1 ? wk : wv);
    wqkvT[id] = __float2bfloat16(W[kk * 256 + c]);
  } else if (id < 458752) {              // wf1T [1024][256]
    const int t = id - 196608;
    const int n = t >> 8, kk = t & 255;
    wf1T[t] = __float2bfloat16(wf1[kk * 1024 + n]);
  } else {                               // wf2T [256][1024]
    const int t = id - 458752;
    const int n = t >> 10, kk = t & 1023;
    wf2T[t] = __float2bfloat16(wf2[kk * 256 + n]);
  }
}

// ---------------- rel-pos bias gather: biasPre[nh][n][m]
__global__ __launch_bounds__(256) void k_bias_pre(
    const float* __restrict__ table, float* __restrict__ biasPre)
{
  const int idx = blockIdx.x * 256 + threadIdx.x;  // 32768
  const int nh = idx >> 12, n = (idx >> 6) & 63, m = idx & 63;
  const int dr = (n >> 3) - (m >> 3) + 7, dc = (n & 7) - (m & 7) + 7;
  biasPre[idx] = table[(dr * 15 + dc) * 8 + nh];
}

// ---------------- fused LN1 + roll + window + QKV GEMM (N=768 looped)
// out: q/k head layout [win][nh][tok][32], v transposed [win][nh][32][tok]
__global__ __launch_bounds__(256, 2) void k_qkv(
    const float* __restrict__ x, const float* __restrict__ g1,
    const float* __restrict__ b1, const __hip_bfloat16* __restrict__ wqkvT,
    const float* __restrict__ bq, const float* __restrict__ bk,
    const float* __restrict__ bv, __hip_bfloat16* __restrict__ qb,
    __hip_bfloat16* __restrict__ kbuf, __hip_bfloat16* __restrict__ vtb)
{
  __shared__ __align__(16) __hip_bfloat16 Alds[128 * 256];   // 64KB, swizzled
  const int tid = threadIdx.x, wid = tid >> 6, lane = tid & 63;
  const int quad = lane >> 4, ln = lane & 15;
  const int mtile = blockIdx.x * 128;

  // ---- LN1 stage: each wave 32 tokens, write bf16 into swizzled Alds
  #pragma unroll 4
  for (int i = 0; i < 32; i++) {
    const int tl = wid * 32 + i;
    const int row = mtile + tl;
    const int win = row >> 6, n = row & 63;
    const int b = win >> 10, wimg = win & 1023, wi = wimg >> 5, wj = wimg & 31;
    const int y = (wi * 8 + (n >> 3) + 4) & 255, xc = (wj * 8 + (n & 7) + 4) & 255;
    float4 v = ((const float4*)(x + ((size_t)(b * 65536 + y * 256 + xc)) * 256))[lane];
    float s  = v.x + v.y + v.z + v.w;
    float sq = v.x*v.x + v.y*v.y + v.z*v.z + v.w*v.w;
    for (int o = 32; o > 0; o >>= 1) { s += __shfl_xor(s, o); sq += __shfl_xor(sq, o); }
    const float mean = s * (1.f/256.f);
    const float rstd = rsqrtf(sq * (1.f/256.f) - mean*mean + 1e-5f);
    const int c0 = lane * 4;
    float vv[4] = {v.x, v.y, v.z, v.w};
    union { __hip_bfloat16 h[4]; uint2 u; } ob;
    #pragma unroll
    for (int jj = 0; jj < 4; jj++)
      ob.h[jj] = __float2bfloat16((vv[jj]-mean)*rstd*g1[c0+jj] + b1[c0+jj]);
    const int seg = c0 >> 5, qc = (c0 >> 3) & 3, j0 = c0 & 7;
    const int qq = qc ^ ((tl >> 1) & 3);
    *(uint2*)&Alds[tl*256 + seg*32 + qq*8 + j0] = ob.u;
  }
  __syncthreads();

  const int wrow = (wid >> 1) * 64, wcol = (wid & 1) * 64;
  for (int nb = 0; nb < 6; nb++) {
    f32x4 acc[4][4];
    #pragma unroll
    for (int mt = 0; mt < 4; mt++)
      #pragma unroll
      for (int nt = 0; nt < 4; nt++) acc[mt][nt] = (f32x4){0.f,0.f,0.f,0.f};
    #pragma unroll
    for (int k0 = 0; k0 < 256; k0 += 32) {
      bf16x8 af[4], bfr[4];
      #pragma unroll
      for (int mt = 0; mt < 4; mt++) {
        const int r = wrow + mt*16 + ln;
        af[mt] = *(const bf16x8*)&Alds[r*256 + k0 + (quad ^ ((r >> 1) & 3))*8];
      }
      #pragma unroll
      for (int nt = 0; nt < 4; nt++) {
        const int nn = nb*128 + wcol + nt*16 + ln;
        bfr[nt] = *(const bf16x8*)(wqkvT + (size_t)nn*256 + k0 + quad*8);
      }
      #pragma unroll
      for (int mt = 0; mt < 4; mt++)
        #pragma unroll
        for (int nt = 0; nt < 4; nt++)
          acc[mt][nt] = __builtin_amdgcn_mfma_f32_16x16x32_bf16(af[mt], bfr[nt], acc[mt][nt], 0, 0, 0);
    }
    // epilogue: scatter to q/k (head layout) or vt (transposed)
    #pragma unroll
    for (int mt = 0; mt < 4; mt++) {
      #pragma unroll
      for (int nt = 0; nt < 4; nt++) {
        const int cB = nb*128 + wcol + nt*16 + ln;
        const int sec = cB >> 8, c = cB & 255, nh = c >> 5, d = c & 31;
        const float bs = (sec == 0 ? bq : (sec == 1 ? bk : bv))[c];
        #pragma unroll
        for (int r = 0; r < 4; r++) {
          const int mB = mtile + wrow + mt*16 + quad*4 + r;
          const int win = mB >> 6, tok = mB & 63;
          const __hip_bfloat16 hv = __float2bfloat16(acc[mt][nt][r] + bs);
          if (sec < 2) {
            __hip_bfloat16* dst = sec == 0 ? qb : kbuf;
            dst[(((size_t)win*8 + nh)*64 + tok)*32 + d] = hv;
          } else {
            vtb[(((size_t)win*8 + nh)*32 + d)*64 + tok] = hv;
          }
        }
      }
    }
  }
}

// ---------------- fused attention + un-window(scramble) + residual + LN2 -> zb
// block=256 (4 waves) per window; wave wv computes heads 2wv,2wv+1 which are
// exactly the heads its 16 output pixels need (head = y2 & 7) -> no barriers.
__global__ __launch_bounds__(256, 2) void k_attn2(
    const __hip_bfloat16* __restrict__ q, const __hip_bfloat16* __restrict__ kbuf,
    const __hip_bfloat16* __restrict__ vt, const float* __restrict__ biasPre,
    const float* __restrict__ x, const float* __restrict__ g2,
    const float* __restrict__ b2, __hip_bfloat16* __restrict__ zb)
{
  __shared__ __align__(16) __hip_bfloat16 Plds[4][64*72];    // 36KB
  __shared__ __align__(16) __hip_bfloat16 Olds[4][2][64*36]; // 36KB
  const int tid = threadIdx.x, wv = tid >> 6, lane = tid & 63;
  const int quad = lane >> 4, ln = lane & 15;
  const int win = blockIdx.x;
  const int b = win >> 10, wimg = win & 1023, wi = wimg >> 5, wj = wimg & 31;

  int colreg[4], rowreg[4][4];
  #pragma unroll
  for (int nt = 0; nt < 4; nt++) {
    const int t = nt*16 + ln;
    const int y = wi*8 + (t >> 3), xx = wj*8 + (t & 7);
    colreg[nt] = ((y < 248) ? 0 : ((y < 252) ? 1 : 2)) * 3 +
                 ((xx < 248) ? 0 : ((xx < 252) ? 1 : 2));
  }
  #pragma unroll
  for (int mt = 0; mt < 4; mt++)
    #pragma unroll
    for (int r = 0; r < 4; r++) {
      const int t = mt*16 + quad*4 + r;
      const int y = wi*8 + (t >> 3), xx = wj*8 + (t & 7);
      rowreg[mt][r] = ((y < 248) ? 0 : ((y < 252) ? 1 : 2)) * 3 +
                      ((xx < 248) ? 0 : ((xx < 252) ? 1 : 2));
    }

  #pragma unroll
  for (int hh = 0; hh < 2; hh++) {
    const int h = wv*2 + hh;
    const size_t base = ((size_t)win*8 + h)*2048;

    bf16x8 af[4], bfr[4];
    #pragma unroll
    for (int mt = 0; mt < 4; mt++)
      af[mt] = *(const bf16x8*)(q + base + (size_t)(mt*16 + ln)*32 + quad*8);
    #pragma unroll
    for (int nt = 0; nt < 4; nt++)
      bfr[nt] = *(const bf16x8*)(kbuf + base + (size_t)(nt*16 + ln)*32 + quad*8);
    f32x4 s[4][4];
    #pragma unroll
    for (int mt = 0; mt < 4; mt++)
      #pragma unroll
      for (int nt = 0; nt < 4; nt++) {
        s[mt][nt] = (f32x4){0.f,0.f,0.f,0.f};
        s[mt][nt] = __builtin_amdgcn_mfma_f32_16x16x32_bf16(af[mt], bfr[nt], s[mt][nt], 0, 0, 0);
      }

    const float* bp = biasPre + (h << 12);
    #pragma unroll
    for (int mt = 0; mt < 4; mt++)
      #pragma unroll
      for (int nt = 0; nt < 4; nt++)
        #pragma unroll
        for (int r = 0; r < 4; r++) {
          const int row = mt*16 + quad*4 + r, col = nt*16 + ln;
          float val = s[mt][nt][r] * 0.17677669529663687f + bp[row*64 + col];
          if (rowreg[mt][r] != colreg[nt]) val -= 100.f;
          s[mt][nt][r] = val;
        }

    #pragma unroll
    for (int mt = 0; mt < 4; mt++) {
      f32x4 mx;
      #pragma unroll
      for (int r = 0; r < 4; r++)
        mx[r] = fmaxf(fmaxf(s[mt][0][r], s[mt][1][r]), fmaxf(s[mt][2][r], s[mt][3][r]));
      #pragma unroll
      for (int msk = 1; msk <= 8; msk <<= 1)
        #pragma unroll
        for (int r = 0; r < 4; r++) mx[r] = fmaxf(mx[r], __shfl_xor(mx[r], msk));
      f32x4 sum = (f32x4){0.f,0.f,0.f,0.f};
      #pragma unroll
      for (int nt = 0; nt < 4; nt++)
        #pragma unroll
        for (int r = 0; r < 4; r++) {
          s[mt][nt][r] = __expf(s[mt][nt][r] - mx[r]);
          sum[r] += s[mt][nt][r];
        }
      #pragma unroll
      for (int msk = 1; msk <= 8; msk <<= 1)
        #pragma unroll
        for (int r = 0; r < 4; r++) sum[r] += __shfl_xor(sum[r], msk);
      #pragma unroll
      for (int nt = 0; nt < 4; nt++)
        #pragma unroll
        for (int r = 0; r < 4; r++)
          Plds[wv][(mt*16 + quad*4 + r)*72 + nt*16 + ln] =
              __float2bfloat16(s[mt][nt][r] / sum[r]);
    }

    f32x4 o[4][2];
    #pragma unroll
    for (int mt = 0; mt < 4; mt++)
      #pragma unroll
      for (int dt = 0; dt < 2; dt++) o[mt][dt] = (f32x4){0.f,0.f,0.f,0.f};
    #pragma unroll
    for (int ks = 0; ks < 2; ks++) {
      bf16x8 pa[4];
      #pragma unroll
      for (int mt = 0; mt < 4; mt++)
        pa[mt] = *(const bf16x8*)&Plds[wv][(mt*16 + ln)*72 + ks*32 + quad*8];
      #pragma unroll
      for (int dt = 0; dt < 2; dt++) {
        const bf16x8 vb = *(const bf16x8*)(vt + base + (size_t)(dt*16 + ln)*64 + ks*32 + quad*8);
        #pragma unroll
        for (int mt = 0; mt < 4; mt++)
          o[mt][dt] = __builtin_amdgcn_mfma_f32_16x16x32_bf16(pa[mt], vb, o[mt][dt], 0, 0, 0);
      }
    }
    #pragma unroll
    for (int mt = 0; mt < 4; mt++)
      #pragma unroll
      for (int dt = 0; dt < 2; dt++)
        #pragma unroll
        for (int r = 0; r < 4; r++)
          Olds[wv][hh][(mt*16 + quad*4 + r)*36 + dt*16 + ln] =
              __float2bfloat16(o[mt][dt][r]);
  }

  // ---- per-wave LN2 over its 16 output pixels (heads 2wv,2wv+1 local)
  #pragma unroll 4
  for (int i = 0; i < 16; i++) {
    const int p = wv*16 + i, py = p >> 3, px = p & 7, hh = i >> 3;
    const int y2 = wi*8 + py, x2 = wj*8 + px;
    const int y = (y2 + 4) & 255, xx = (x2 + 4) & 255;
    const size_t t = (size_t)b*65536 + y*256 + xx;
    const int c0 = lane * 4;
    const int nn = px*8 + (c0 >> 5), d = c0 & 31;
    union { __hip_bfloat16 h[4]; uint2 u; } ou;
    ou.u = *(const uint2*)&Olds[wv][hh][nn*36 + d];
    float4 xv = ((const float4*)(x + t*256))[lane];
    float sv[4];
    sv[0] = xv.x + __bfloat162float(ou.h[0]);
    sv[1] = xv.y + __bfloat162float(ou.h[1]);
    sv[2] = xv.z + __bfloat162float(ou.h[2]);
    sv[3] = xv.w + __bfloat162float(ou.h[3]);
    float s  = sv[0]+sv[1]+sv[2]+sv[3];
    float sq = sv[0]*sv[0]+sv[1]*sv[1]+sv[2]*sv[2]+sv[3]*sv[3];
    for (int o = 32; o > 0; o >>= 1) { s += __shfl_xor(s, o); sq += __shfl_xor(sq, o); }
    const float mean = s*(1.f/256.f);
    const float rstd = rsqrtf(sq*(1.f/256.f) - mean*mean + 1e-5f);
    union { __hip_bfloat16 h[4]; uint2 u; } ob;
    #pragma unroll
    for (int jj = 0; jj < 4; jj++)
      ob.h[jj] = __float2bfloat16((sv[jj]-mean)*rstd*g2[c0+jj] + b2[c0+jj]);
    *(uint2*)(zb + t*256 + c0) = ob.u;
  }
}

// ---------------- fused MLP: FC1 -> GELU -> FC2 (+bias +zb residual) -> d_out fp32
// 64-token blocks; Z LDS-resident; H chunk [64x128] round-trips LDS; B from L2.
__global__ __launch_bounds__(256, 2) void k_mlp(
    const __hip_bfloat16* __restrict__ zb, const __hip_bfloat16* __restrict__ wf1T,
    const __hip_bfloat16* __restrict__ wf2T, const float* __restrict__ bf1,
    const float* __restrict__ bf2, float* __restrict__ out)
{
  __shared__ __align__(16) __hip_bfloat16 Zlds[64 * 256];   // 32KB, swizzled
  __shared__ __align__(16) __hip_bfloat16 Hlds[64 * 128];   // 16KB, swizzled
  const int tid = threadIdx.x, w = tid >> 6, lane = tid & 63;
  const int quad = lane >> 4, ln = lane & 15;
  const int m0 = blockIdx.x * 64;

  // stage Z: 2048 chunks of 16B via global_load_lds (slot inversion of swizzle)
  #pragma unroll
  for (int pass = 0; pass < 8; pass++) {
    const int base = pass*256 + w*64;
    const int L = base + lane;
    const int tok = L >> 5, kc = L & 31;
    const int seg = kc >> 2, qq = (kc & 3) ^ ((tok >> 1) & 3);
    gload_lds16(zb + (size_t)(m0 + tok)*256 + seg*32 + qq*8, Zlds + (size_t)base*8);
  }
  __syncthreads();

  f32x4 acc2[4][4];
  #pragma unroll
  for (int mt = 0; mt < 4; mt++)
    #pragma unroll
    for (int nt = 0; nt < 4; nt++) acc2[mt][nt] = (f32x4){0.f,0.f,0.f,0.f};

  for (int hc = 0; hc < 8; hc++) {
    // ---- FC1 chunk: H[64 x 128], wave w computes hidden cols [w*32, w*32+32)
    f32x4 a1[4][2];
    #pragma unroll
    for (int mt = 0; mt < 4; mt++)
      #pragma unroll
      for (int nt = 0; nt < 2; nt++) a1[mt][nt] = (f32x4){0.f,0.f,0.f,0.f};
    #pragma unroll
    for (int k0 = 0; k0 < 256; k0 += 32) {
      bf16x8 za[4], b1f[2];
      #pragma unroll
      for (int mt = 0; mt < 4; mt++) {
        const int m = mt*16 + ln;
        za[mt] = *(const bf16x8*)&Zlds[m*256 + k0 + (quad ^ ((m >> 1) & 3))*8];
      }
      #pragma unroll
      for (int nt = 0; nt < 2; nt++) {
        const int n1 = hc*128 + w*32 + nt*16 + ln;
        b1f[nt] = *(const bf16x8*)(wf1T + (size_t)n1*256 + k0 + quad*8);
      }
      #pragma unroll
      for (int mt = 0; mt < 4; mt++)
        #pragma unroll
        for (int nt = 0; nt < 2; nt++)
          a1[mt][nt] = __builtin_amdgcn_mfma_f32_16x16x32_bf16(za[mt], b1f[nt], a1[mt][nt], 0, 0, 0);
    }
    // GELU + swizzled Hlds write
    #pragma unroll
    for (int mt = 0; mt < 4; mt++)
      #pragma unroll
      for (int nt = 0; nt < 2; nt++) {
        const int n = w*32 + nt*16 + ln;
        const float bs = bf1[hc*128 + n];
        const int seg = n >> 5, qn = (n >> 3) & 3, j = n & 7;
        #pragma unroll
        for (int r = 0; r < 4; r++) {
          const int m1 = mt*16 + quad*4 + r;
          const float u = gelu_fast(a1[mt][nt][r] + bs);
          Hlds[m1*128 + seg*32 + (qn ^ ((m1 >> 1) & 3))*8 + j] = __float2bfloat16(u);
        }
      }
    __syncthreads();
    // ---- FC2 partial: out[64 x 256] += H @ wf2T_chunk, wave w cols [w*64,+64)
    #pragma unroll
    for (int ks = 0; ks < 4; ks++) {
      bf16x8 ha[4];
      #pragma unroll
      for (int mt = 0; mt < 4; mt++) {
        const int m = mt*16 + ln;
        ha[mt] = *(const bf16x8*)&Hlds[m*128 + ks*32 + (quad ^ ((m >> 1) & 3))*8];
      }
      #pragma unroll
      for (int nt = 0; nt < 4; nt++) {
        const int n2 = w*64 + nt*16 + ln;
        const bf16x8 b2f = *(const bf16x8*)(wf2T + (size_t)n2*1024 + hc*128 + ks*32 + quad*8);
        #pragma unroll
        for (int mt = 0; mt < 4; mt++)
          acc2[mt][nt] = __builtin_amdgcn_mfma_f32_16x16x32_bf16(ha[mt], b2f, acc2[mt][nt], 0, 0, 0);
      }
    }
    __syncthreads();
  }

  // epilogue: + bias + zb residual, fp32 out
  #pragma unroll
  for (int mt = 0; mt < 4; mt++) {
    #pragma unroll
    for (int nt = 0; nt < 4; nt++) {
      const int cB = w*64 + nt*16 + ln;
      const float bs = bf2[cB];
      #pragma unroll
      for (int r = 0; r < 4; r++) {
        const int mB = m0 + mt*16 + quad*4 + r;
        out[(size_t)mB*256 + cB] = acc2[mt][nt][r] + bs +
            __bfloat162float(zb[(size_t)mB*256 + cB]);
      }
    }
  }
}

extern "C" void kernel_launch(void* const* d_in, const int* in_sizes, int n_in,
                              void* d_out, int out_size, void* d_ws, size_t ws_size,
                              hipStream_t stream)
{
  (void)in_sizes; (void)n_in; (void)out_size; (void)ws_size;
  const float* x   = (const float*)d_in[0];
  const float* g1  = (const float*)d_in[1];
  const float* b1  = (const float*)d_in[2];
  const float* wq  = (const float*)d_in[3];
  const float* bq  = (const float*)d_in[4];
  const float* wk  = (const float*)d_in[5];
  const float* bk  = (const float*)d_in[6];
  const float* wv  = (const float*)d_in[7];
  const float* bv  = (const float*)d_in[8];
  const float* tbl = (const float*)d_in[9];
  const float* g2  = (const float*)d_in[10];
  const float* b2  = (const float*)d_in[11];
  const float* wf1 = (const float*)d_in[12];
  const float* bf1 = (const float*)d_in[13];
  const float* wf2 = (const float*)d_in[14];
  const float* bf2 = (const float*)d_in[15];

  char* ws = (char*)d_ws;
  const size_t MB = 1024ull*1024ull;
  __hip_bfloat16* qb    = (__hip_bfloat16*)(ws);             // 64MB
  __hip_bfloat16* kb    = (__hip_bfloat16*)(ws + 64*MB);     // 64MB
  __hip_bfloat16* vtb   = (__hip_bfloat16*)(ws + 128*MB);    // 64MB
  __hip_bfloat16* zb    = (__hip_bfloat16*)(ws + 192*MB);    // 64MB
  float*          biasP = (float*)(ws + 256*MB);             // 128KB
  __hip_bfloat16* wqkvT = (__hip_bfloat16*)(ws + 257*MB);    // 384KB
  __hip_bfloat16* wf1T  = (__hip_bfloat16*)(ws + 258*MB);    // 512KB
  __hip_bfloat16* wf2T  = (__hip_bfloat16*)(ws + 259*MB);    // 512KB

  k_pack<<<2816, 256, 0, stream>>>(wq, wk, wv, wf1, wf2, wqkvT, wf1T, wf2T);
  k_bias_pre<<<128, 256, 0, stream>>>(tbl, biasP);
  k_qkv<<<1024, 256, 0, stream>>>(x, g1, b1, wqkvT, bq, bk, bv, qb, kb, vtb);
  k_attn2<<<BW_, 256, 0, stream>>>(qb, kb, vtb, biasP, x, g2, b2, zb);
  k_mlp<<<2048, 256, 0, stream>>>(zb, wf1T, wf2T, bf1, bf2, (float*)d_out);
}